// Round 6
// baseline (390.106 us; speedup 1.0000x reference)
//
#include <hip/hip_runtime.h>

#define DD 128   // feature dim, fixed by the reference

// Per-element update: z = x*a + c; z2 = z*z; p *= (1 - z2); s += z2.
#define UPD4(P, S, XV)                                                          \
    {                                                                           \
        float z, z2;                                                            \
        z = fmaf((XV).x, av.x, cv.x); z2 = z * z; P = fmaf(-z2, P, P); S += z2; \
        z = fmaf((XV).y, av.y, cv.y); z2 = z * z; P = fmaf(-z2, P, P); S += z2; \
        z = fmaf((XV).z, av.z, cv.z); z2 = z * z; P = fmaf(-z2, P, P); S += z2; \
        z = fmaf((XV).w, av.w, cv.w); z2 = z * z; P = fmaf(-z2, P, P); S += z2; \
    }

// Shared staging: a = 1/scale, c = -bias/scale -> LDS [64 rows][32 quads],
// quad slot XOR-swizzled by (row&7). Read as arow[q ^ (lane&7)] -> quad q of
// row=lane (matched pairing with x[q] -- verified: slot q^s holds quad
// (q^s)^s = q). Conflict-free at the b128 minimum.
#define STAGE_AC()                                                              \
    {                                                                           \
        const float4* b4 = (const float4*)(bias  + (size_t)n0 * DD);            \
        const float4* s4 = (const float4*)(scale + (size_t)n0 * DD);            \
        _Pragma("unroll")                                                       \
        for (int k = 0; k < 4; ++k) {                                           \
            int flat = tid + k * 512;                                           \
            int r = flat >> 5;                                                  \
            int q = flat & 31;                                                  \
            float4 sv = s4[flat];                                               \
            float4 bv = b4[flat];                                               \
            float4 av, cv;                                                      \
            av.x = 1.0f / sv.x; av.y = 1.0f / sv.y;                             \
            av.z = 1.0f / sv.z; av.w = 1.0f / sv.w;                             \
            cv.x = -bv.x * av.x; cv.y = -bv.y * av.y;                           \
            cv.z = -bv.z * av.z; cv.w = -bv.w * av.w;                           \
            int dst = r * 32 + (q ^ (r & 7));                                   \
            a_s[dst] = av;                                                      \
            c_s[dst] = cv;                                                      \
        }                                                                       \
    }

#define PREAMBLE()                                        \
    __shared__ float4 a_s[64 * 32];                       \
    __shared__ float4 c_s[64 * 32];                       \
    const int tid  = threadIdx.x;                         \
    const int lane = tid & 63;                            \
    const int wave = tid >> 6;                            \
    const int n0 = blockIdx.x * 64;                       \
    const int bb = blockIdx.y * 32;                       \
    STAGE_AC();                                           \
    __syncthreads();                                      \
    const float4* arow = a_s + lane * 32;                 \
    const float4* crow = c_s + lane * 32;                 \
    const int sw = lane & 7;                              \
    (void)arow; (void)crow; (void)sw;

// ======================= real kernel: R1 + builtin exp2 =======================
__global__ __launch_bounds__(512, 4)
void wavelet_prod_kernel(const float* __restrict__ x,
                         const float* __restrict__ bias,
                         const float* __restrict__ scale,
                         float* __restrict__ out,
                         int B, int N)
{
    PREAMBLE();

    const int b0 = __builtin_amdgcn_readfirstlane(bb + wave * 4);
    const float4* xr = (const float4*)(x + (size_t)b0 * DD);

    float p0 = 1.f, p1 = 1.f, p2 = 1.f, p3 = 1.f;
    float s0 = 0.f, s1 = 0.f, s2 = 0.f, s3 = 0.f;
    const float kexp = -0.7213475204444817f;  // -0.5 * log2(e)

    #pragma unroll
    for (int f = 0; f < 8; ++f) {
        #pragma unroll
        for (int cc = 0; cc < 4; ++cc) {
            const int q    = f * 4 + cc;
            const int slot = q ^ sw;
            float4 av = arow[slot];
            float4 cv = crow[slot];
            float4 x0 = xr[q];
            float4 x1 = xr[32 + q];
            float4 x2 = xr[64 + q];
            float4 x3 = xr[96 + q];
            UPD4(p0, s0, x0);
            UPD4(p1, s1, x1);
            UPD4(p2, s2, x2);
            UPD4(p3, s3, x3);
        }
        p0 *= __builtin_amdgcn_exp2f(s0 * kexp); s0 = 0.f;
        p1 *= __builtin_amdgcn_exp2f(s1 * kexp); s1 = 0.f;
        p2 *= __builtin_amdgcn_exp2f(s2 * kexp); s2 = 0.f;
        p3 *= __builtin_amdgcn_exp2f(s3 * kexp); s3 = 0.f;
    }

    float* o = out + (size_t)b0 * N + n0 + lane;
    o[0 * N] = p0;
    o[1 * N] = p1;
    o[2 * N] = p2;
    o[3 * N] = p3;
}

// ======================= named diagnostics (write to d_ws) =======================
// diag_full  x6  : R1 loop, rep-rotated indices (baseline per-rep cost R)
// diag_nolds x6  : a/c hoisted to regs, x loads remain (LDS-path cost)
// diag_vecx  x6  : x via divergent vector loads (vmcnt) -- lgkmcnt-mixing test
// diag_novalu x24: loads only, asm keepalive, no math (latency-vs-VALU decider)

#define DIAG_BODY(REPS, GET_AC, GET_X, DO_MATH, DO_FOLD)                        \
    float p0 = 1.f, p1 = 1.f, p2 = 1.f, p3 = 1.f;                               \
    float s0 = 0.f, s1 = 0.f, s2 = 0.f, s3 = 0.f;                               \
    _Pragma("unroll 1")                                                         \
    for (int rep = 0; rep < REPS; ++rep) {                                      \
        _Pragma("unroll")                                                       \
        for (int f = 0; f < 8; ++f) {                                           \
            _Pragma("unroll")                                                   \
            for (int cc = 0; cc < 4; ++cc) {                                    \
                const int qi   = ((f * 4 + cc) + rep) & 31;  /* defeats LICM */ \
                const int slot = qi ^ sw;                                       \
                float4 av, cv, x0, x1, x2, x3;                                  \
                GET_AC();                                                       \
                GET_X();                                                        \
                DO_MATH();                                                      \
            }                                                                   \
            DO_FOLD();                                                          \
        }                                                                       \
    }                                                                           \
    float* o = out + (size_t)b0 * N + n0 + lane;                                \
    o[0 * N] = p0; o[1 * N] = p1; o[2 * N] = p2; o[3 * N] = p3;

#define AC_LDS()   { av = arow[slot]; cv = crow[slot]; }
#define X_GLB()    { x0 = xr[qi]; x1 = xr[32 + qi]; x2 = xr[64 + qi]; x3 = xr[96 + qi]; }
#define MATH_FULL() { UPD4(p0, s0, x0); UPD4(p1, s1, x1); UPD4(p2, s2, x2); UPD4(p3, s3, x3); }
#define FOLD_EXP() {                                                     \
    const float kexp = -0.7213475204444817f;                             \
    p0 *= __builtin_amdgcn_exp2f(s0 * kexp); s0 = 0.f;                   \
    p1 *= __builtin_amdgcn_exp2f(s1 * kexp); s1 = 0.f;                   \
    p2 *= __builtin_amdgcn_exp2f(s2 * kexp); s2 = 0.f;                   \
    p3 *= __builtin_amdgcn_exp2f(s3 * kexp); s3 = 0.f; }

__global__ __launch_bounds__(512, 4)
void diag_full(const float* __restrict__ x, const float* __restrict__ bias,
               const float* __restrict__ scale, float* __restrict__ out, int B, int N)
{
    PREAMBLE();
    const int b0 = __builtin_amdgcn_readfirstlane(bb + wave * 4);
    const float4* xr = (const float4*)(x + (size_t)b0 * DD);
    DIAG_BODY(6, AC_LDS, X_GLB, MATH_FULL, FOLD_EXP);
}

__global__ __launch_bounds__(512, 4)
void diag_nolds(const float* __restrict__ x, const float* __restrict__ bias,
                const float* __restrict__ scale, float* __restrict__ out, int B, int N)
{
    PREAMBLE();
    const int b0 = __builtin_amdgcn_readfirstlane(bb + wave * 4);
    const float4* xr = (const float4*)(x + (size_t)b0 * DD);
    float4 avP = arow[sw], cvP = crow[sw];   // one-time LDS read
    #define AC_REG() { av = avP; cv = cvP; }
    DIAG_BODY(6, AC_REG, X_GLB, MATH_FULL, FOLD_EXP);
    #undef AC_REG
}

__global__ __launch_bounds__(512, 4)
void diag_vecx(const float* __restrict__ x, const float* __restrict__ bias,
               const float* __restrict__ scale, float* __restrict__ out, int B, int N)
{
    PREAMBLE();
    const int b0 = bb + wave * 4;            // no readfirstlane
    // mbcnt(1,0): lane0 -> 0, others -> 1. Genuinely divergent -> forces
    // per-lane global_load_dwordx4 (vmcnt domain), decoupled from lgkmcnt.
    unsigned dz = __builtin_amdgcn_mbcnt_lo(1u, 0u);
    const float4* xr = (const float4*)(x + (size_t)b0 * DD + dz);
    DIAG_BODY(6, AC_LDS, X_GLB, MATH_FULL, FOLD_EXP);
}

__global__ __launch_bounds__(512, 4)
void diag_novalu(const float* __restrict__ x, const float* __restrict__ bias,
                 const float* __restrict__ scale, float* __restrict__ out, int B, int N)
{
    PREAMBLE();
    const int b0 = __builtin_amdgcn_readfirstlane(bb + wave * 4);
    const float4* xr = (const float4*)(x + (size_t)b0 * DD);
    // Loads only; asm keepalive prevents DCE (guide rule #17) at zero cost.
    #define MATH_KEEP() {                                                        \
        asm volatile("" :: "v"(av.x), "v"(av.y), "v"(av.z), "v"(av.w),           \
                           "v"(cv.x), "v"(cv.y), "v"(cv.z), "v"(cv.w),           \
                           "v"(x0.x), "v"(x0.y), "v"(x0.z), "v"(x0.w),           \
                           "v"(x1.x), "v"(x1.y), "v"(x1.z), "v"(x1.w),           \
                           "v"(x2.x), "v"(x2.y), "v"(x2.z), "v"(x2.w),           \
                           "v"(x3.x), "v"(x3.y), "v"(x3.z), "v"(x3.w)); }
    #define FOLD_NONE() {}
    DIAG_BODY(24, AC_LDS, X_GLB, MATH_KEEP, FOLD_NONE);
    #undef MATH_KEEP
    #undef FOLD_NONE
}

extern "C" void kernel_launch(void* const* d_in, const int* in_sizes, int n_in,
                              void* d_out, int out_size, void* d_ws, size_t ws_size,
                              hipStream_t stream)
{
    const float* x     = (const float*)d_in[0];
    const float* bias  = (const float*)d_in[1];
    const float* scale = (const float*)d_in[2];
    float* out = (float*)d_out;

    const int B = in_sizes[0] / DD;   // 2048
    const int N = in_sizes[1] / DD;   // 512

    dim3 grid(N / 64, B / 32);        // (8, 64) = 512 blocks
    wavelet_prod_kernel<<<grid, 512, 0, stream>>>(x, bias, scale, out, B, N);

    if (ws_size >= 4 * (size_t)out_size * sizeof(float)) {
        float* w = (float*)d_ws;
        diag_full  <<<grid, 512, 0, stream>>>(x, bias, scale, w + 0 * (size_t)out_size, B, N);
        diag_nolds <<<grid, 512, 0, stream>>>(x, bias, scale, w + 1 * (size_t)out_size, B, N);
        diag_vecx  <<<grid, 512, 0, stream>>>(x, bias, scale, w + 2 * (size_t)out_size, B, N);
        diag_novalu<<<grid, 512, 0, stream>>>(x, bias, scale, w + 3 * (size_t)out_size, B, N);
    }
}

// Round 7
// 303.276 us; speedup vs baseline: 1.2863x; 1.2863x over previous
//
#include <hip/hip_runtime.h>

#define DD 128   // feature dim, fixed by the reference

// Per-element update: z = x*a + c; z2 = z*z; p *= (1 - z2); s += z2.
#define UPD4(P, S, XV, AV, CV)                                                      \
    {                                                                               \
        float z, z2;                                                                \
        z = fmaf((XV).x, (AV).x, (CV).x); z2 = z * z; P = fmaf(-z2, P, P); S += z2; \
        z = fmaf((XV).y, (AV).y, (CV).y); z2 = z * z; P = fmaf(-z2, P, P); S += z2; \
        z = fmaf((XV).z, (AV).z, (CV).z); z2 = z * z; P = fmaf(-z2, P, P); S += z2; \
        z = fmaf((XV).w, (AV).w, (CV).w); z2 = z * z; P = fmaf(-z2, P, P); S += z2; \
    }

// a = 1/scale, c = -bias/scale -> LDS [64 rows][32 quads], quad slot XOR-
// swizzled by (row&7). Compute reads arow[q ^ (lane&7)] = quad q of row=lane
// (slot q^s holds quad (q^s)^s = q -- pairing verified).
template<int REPS>
__device__ __forceinline__
void wavelet_body(const float* __restrict__ x,
                  const float* __restrict__ bias,
                  const float* __restrict__ scale,
                  float* __restrict__ out, int N)
{
    __shared__ float4 a_s[64 * 32];
    __shared__ float4 c_s[64 * 32];

    const int tid  = threadIdx.x;
    const int lane = tid & 63;
    const int wave = tid >> 6;
    const int n0 = blockIdx.x * 64;   // 64 n per block (one per lane)
    const int bb = blockIdx.y * 64;   // 64 b per block (8 per wave/thread)

    {
        const float4* b4 = (const float4*)(bias  + (size_t)n0 * DD);
        const float4* s4 = (const float4*)(scale + (size_t)n0 * DD);
        #pragma unroll
        for (int k = 0; k < 4; ++k) {
            int flat = tid + k * 512;          // 0..2047 float4 slots
            int r = flat >> 5;
            int q = flat & 31;
            float4 sv = s4[flat];
            float4 bv = b4[flat];
            float4 av, cv;
            av.x = 1.0f / sv.x; av.y = 1.0f / sv.y;
            av.z = 1.0f / sv.z; av.w = 1.0f / sv.w;
            cv.x = -bv.x * av.x; cv.y = -bv.y * av.y;
            cv.z = -bv.z * av.z; cv.w = -bv.w * av.w;
            int dst = r * 32 + (q ^ (r & 7));
            a_s[dst] = av;
            c_s[dst] = cv;
        }
    }
    __syncthreads();

    const int b0 = __builtin_amdgcn_readfirstlane(bb + wave * 8);
    const float4* xr = (const float4*)(x + (size_t)b0 * DD);  // rows stride 32 quads

    const float4* arow = a_s + lane * 32;
    const float4* crow = c_s + lane * 32;
    const int sw = lane & 7;

    float p[8], s[8];
    #pragma unroll
    for (int r = 0; r < 8; ++r) { p[r] = 1.f; s[r] = 0.f; }

    const float kexp = -0.7213475204444817f;  // -0.5 * log2(e)

    #pragma unroll 1
    for (int rep = 0; rep < REPS; ++rep) {
        // ---- software-pipelined: prefetch quad q+1 while computing quad q ----
        float4 av, cv, av_n, cv_n, xq[8], xq_n[8];
        {
            const int q0 = (0 + rep) & 31;    // rep-rotation defeats LICM (rep=0: identity)
            av = arow[q0 ^ sw];
            cv = crow[q0 ^ sw];
            #pragma unroll
            for (int r = 0; r < 8; ++r) xq[r] = xr[r * 32 + q0];
        }
        #pragma unroll
        for (int f = 0; f < 8; ++f) {
            #pragma unroll
            for (int cc = 0; cc < 4; ++cc) {
                const int q = f * 4 + cc;
                if (q < 31 || REPS > 1) {     // issue next-quad loads first
                    const int qn   = (q + 1 + rep) & 31;
                    const int slot = qn ^ sw;
                    av_n = arow[slot];
                    cv_n = crow[slot];
                    #pragma unroll
                    for (int r = 0; r < 8; ++r) xq_n[r] = xr[r * 32 + qn];
                }
                #pragma unroll
                for (int r = 0; r < 8; ++r) UPD4(p[r], s[r], xq[r], av, cv);
                av = av_n; cv = cv_n;
                #pragma unroll
                for (int r = 0; r < 8; ++r) xq[r] = xq_n[r];
            }
            #pragma unroll
            for (int r = 0; r < 8; ++r) {     // fold every 16 d: bounded partials
                p[r] *= __builtin_amdgcn_exp2f(s[r] * kexp);
                s[r] = 0.f;
            }
        }
    }

    float* o = out + (size_t)b0 * N + n0 + lane;
    #pragma unroll
    for (int r = 0; r < 8; ++r) o[r * N] = p[r];
}

// ======================= real kernel (REPS=1) =======================
__global__ __launch_bounds__(512, 2)
void wavelet_prod_kernel(const float* __restrict__ x,
                         const float* __restrict__ bias,
                         const float* __restrict__ scale,
                         float* __restrict__ out,
                         int B, int N)
{
    wavelet_body<1>(x, bias, scale, out, N);
}

// ============ diagnostic: same structure x6, distinct name (-> d_ws) ============
__global__ __launch_bounds__(512, 2)
void diag_real6(const float* __restrict__ x,
                const float* __restrict__ bias,
                const float* __restrict__ scale,
                float* __restrict__ out,
                int B, int N)
{
    wavelet_body<6>(x, bias, scale, out, N);
}

extern "C" void kernel_launch(void* const* d_in, const int* in_sizes, int n_in,
                              void* d_out, int out_size, void* d_ws, size_t ws_size,
                              hipStream_t stream)
{
    const float* x     = (const float*)d_in[0];
    const float* bias  = (const float*)d_in[1];
    const float* scale = (const float*)d_in[2];
    float* out = (float*)d_out;

    const int B = in_sizes[0] / DD;   // 2048
    const int N = in_sizes[1] / DD;   // 512

    dim3 grid(N / 64, B / 64);        // (8, 32) = 256 blocks = 1 per CU
    wavelet_prod_kernel<<<grid, 512, 0, stream>>>(x, bias, scale, out, B, N);

    if (ws_size >= (size_t)out_size * sizeof(float)) {
        diag_real6<<<grid, 512, 0, stream>>>(x, bias, scale, (float*)d_ws, B, N);
    }
}